// Round 10
// baseline (1271.203 us; speedup 1.0000x reference)
//
#include <hip/hip_runtime.h>

#define NB 64
#define NC 32
#define NH 16
#define NW 16
#define NE 4096
#define NTOT (NB*NC*NH*NW)   // 524288
#define IDXW 341             // 1+4+16+64+256
#define GRID 256
#define TPB 1024
#define NBAR 7

__device__ __forceinline__ double cubicw(double x) {
  const double A = -0.75;
  x = fabs(x);
  if (x <= 1.0) return ((A + 2.0) * x - (A + 3.0)) * x * x + 1.0;
  if (x < 2.0)  return A * (((x - 5.0) * x + 8.0) * x - 4.0);
  return 0.0;
}

// One-shot software grid barrier. GRID=256 = #CUs -> all blocks co-resident.
// Poll is a relaxed atomic LOAD (no RMW storm); fences are explicit.
__device__ __forceinline__ void gridbar(unsigned* bar) {
  __syncthreads();
  if (threadIdx.x == 0) {
    __threadfence();   // release: L2 writeback (cross-XCD visibility)
    __hip_atomic_fetch_add(bar, 1u, __ATOMIC_RELAXED, __HIP_MEMORY_SCOPE_AGENT);
    while (__hip_atomic_load(bar, __ATOMIC_RELAXED, __HIP_MEMORY_SCOPE_AGENT) < (unsigned)GRID)
      __builtin_amdgcn_s_sleep(32);
    __threadfence();   // acquire: invalidate stale
  }
  __syncthreads();
}

// Nearest-codebook search for 8 rows starting at flat row n0 (row n -> b,y,x).
// Results left in wd[0..7]/wi[0..7]. Rows j>=valid compute a clamped duplicate
// (caller discards). Per-element math identical to rounds 8/9 (passing).
__device__ __forceinline__ void argmin8(
    const double* __restrict__ z_res, const float* __restrict__ emb_t,
    const double* __restrict__ emb_sq, int ph, int f, int n0, int valid,
    double* rv, double* wd, int* wi, int tid)
{
  if (tid < 256) {
    int j = tid >> 5, c = tid & 31;
    int jj = (j < valid) ? j : (valid - 1);
    int n = n0 + jj;
    int x = n % ph, y = (n / ph) % ph, b = n / (ph * ph);
    const double* base = z_res + (((b * NC + c) * NH) + y * f) * NW + x * f;
    double s = 0.0;
    for (int dy = 0; dy < f; dy++)
      for (int dx = 0; dx < f; dx++) s += base[dy * NW + dx];
    rv[j * NC + c] = s / (double)(f * f);
  }
  __syncthreads();
  double best[8]; int bidx[8];
  #pragma unroll
  for (int j = 0; j < 8; j++) { best[j] = 1e300; bidx[j] = 0; }
  #pragma unroll
  for (int pass = 0; pass < 2; pass++) {     // 1024 thr x 2 entries x 2 passes
    int e0 = pass * 2048 + tid * 2;
    double acc[8][2];
    #pragma unroll
    for (int j = 0; j < 8; j++) { acc[j][0] = 0.0; acc[j][1] = 0.0; }
    #pragma unroll 4
    for (int k = 0; k < NC; k++) {
      float2 e2 = *(const float2*)(emb_t + k * NE + e0);  // coalesced 8B/lane
      double d0 = e2.x, d1 = e2.y;
      #pragma unroll
      for (int j = 0; j < 8; j++) {
        double rj = rv[j * NC + k];
        acc[j][0] += rj * d0; acc[j][1] += rj * d1;
      }
    }
    #pragma unroll
    for (int v = 0; v < 2; v++) {            // ascending e per thread
      double esq = emb_sq[e0 + v];
      #pragma unroll
      for (int j = 0; j < 8; j++) {
        double d = esq - 2.0 * acc[j][v];
        if (d < best[j]) { best[j] = d; bidx[j] = e0 + v; }
      }
    }
  }
  #pragma unroll
  for (int j = 0; j < 8; j++) {              // wave butterfly (min, tie->low idx)
    double d = best[j]; int bi2 = bidx[j];
    #pragma unroll
    for (int off = 32; off >= 1; off >>= 1) {
      double od = __shfl_xor(d, off, 64);
      int oi = __shfl_xor(bi2, off, 64);
      if (od < d || (od == d && oi < bi2)) { d = od; bi2 = oi; }
    }
    best[j] = d; bidx[j] = bi2;
  }
  int wave = tid >> 6, lane = tid & 63;
  if (lane == 0) {
    #pragma unroll
    for (int j = 0; j < 8; j++) { wd[wave * 8 + j] = best[j]; wi[wave * 8 + j] = bidx[j]; }
  }
  __syncthreads();
  if (tid < 8) {                             // cross-wave reduce into slot 0
    double d = wd[tid]; int bi2 = wi[tid];
    #pragma unroll
    for (int w2 = 1; w2 < 16; w2++) {
      double od = wd[w2 * 8 + tid]; int oi = wi[w2 * 8 + tid];
      if (od < d || (od == d && oi < bi2)) { d = od; bi2 = oi; }
    }
    wd[tid] = d; wi[tid] = bi2;
  }
  __syncthreads();
}

__global__ __launch_bounds__(TPB, 4) void k_fused(
    const float* __restrict__ z, const float* __restrict__ emb,
    const float* __restrict__ phi_w, const float* __restrict__ phi_b,
    double* __restrict__ z_res, double* __restrict__ emb_sq,
    double* __restrict__ loss_d, float* __restrict__ emb_t,
    int* __restrict__ idx_ws, unsigned* __restrict__ bars,
    float* __restrict__ out_zhat, float* __restrict__ out_loss,
    float* __restrict__ out_idx)
{
  __shared__ double lds[8192];   // 64 KB, overlaid per phase
  const int tid = threadIdx.x;
  const int bid = blockIdx.x;

  // Poisoned (0xAA) one-shot barrier counters: idempotent CAS by every block.
  if (tid < NBAR) atomicCAS(&bars[tid], 0xAAAAAAAAu, 0u);
  __syncthreads();

  // ---------- setup: z_res init + emb transpose + emb_sq ----------
  for (int i = bid * TPB + tid; i < NTOT; i += GRID * TPB)
    z_res[i] = (double)z[i];
  if (bid == 0 && tid == 0) *loss_d = 0.0;
  if (bid < 64) {
    float* tile = (float*)lds;            // [64][33]
    int e0 = bid * 64;
    for (int t = tid; t < 2048; t += TPB) {
      int el = t >> 5, c = t & 31;
      tile[el * 33 + c] = emb[(e0 + el) * NC + c];
    }
    __syncthreads();
    for (int t = tid; t < 2048; t += TPB) {
      int c = t >> 6, ep = t & 63;
      emb_t[c * NE + e0 + ep] = tile[ep * 33 + c];
    }
    if (tid < 64) {
      const float* tr = &tile[tid * 33];
      double s = 0.0;
      #pragma unroll
      for (int j = 0; j < 8; j++)
        s += (double)tr[4*j]*tr[4*j] + (double)tr[4*j+1]*tr[4*j+1]
           + (double)tr[4*j+2]*tr[4*j+2] + (double)tr[4*j+3]*tr[4*j+3];
      emb_sq[e0 + tid] = s;
    }
  }
  gridbar(&bars[0]);

  const int phs[5]  = {1, 2, 4, 8, 16};
  // ticks = np.linspace(1/12, 11/12, 4) f64: si=2 real-arithmetic tie breaks
  // to pi=2 via 2-ulp linspace rounding (verified by exact mantissa calc).
  const int pis[5]  = {0, 1, 2, 2, 3};
  const int offs[5] = {0, 1, 5, 21, 85};

  const int pix = tid & 255, sub = tid >> 8;        // phi/upsample mapping
  const int px = pix & 15, py = pix >> 4;

  for (int si = 0; si < 5; si++) {
    const int ph = phs[si], f = NH / ph;
    const int idx_off = offs[si];
    const int pi = pis[si];
    const bool worker = ((bid & 3) == 0);           // 64 image-blocks, XCD-spread
    const int b = bid >> 2;

    if (si == 4) {
      // ---- spread argmin over all 256 blocks (8 chunks each) ----
      double* rv = lds; double* wd = lds + 256; int* wi = (int*)(lds + 384);
      for (int chunk = bid; chunk < 2048; chunk += GRID) {
        argmin8(z_res, emb_t, emb_sq, 16, 1, chunk * 8, 8, rv, wd, wi, tid);
        if (tid < 8) {
          int n = chunk * 8 + tid;
          int bi2 = wi[tid];
          idx_ws[n] = bi2;
          out_idx[(n >> 8) * IDXW + 85 + (n & 255)] = (float)bi2;
        }
      }
      gridbar(&bars[5]);
    }

    if (worker) {
      double* qimg = lds;                 // [32][256] = 64 KB
      if (si < 4) {
        // ---- in-block argmin for this image's R rows (idx stays in LDS) ----
        int R = ph * ph;
        double* rv = lds; double* wd = lds + 256; int* wi = (int*)(lds + 384);
        int* idx_loc = (int*)(lds + 448);          // up to 64 ints
        for (int r0 = 0; r0 < R; r0 += 8) {
          int valid = (R - r0 < 8) ? (R - r0) : 8;
          argmin8(z_res, emb_t, emb_sq, ph, f, b * R + r0, valid, rv, wd, wi, tid);
          if (tid < valid) {
            int bi2 = wi[tid];
            idx_loc[r0 + tid] = bi2;
            out_idx[b * IDXW + idx_off + r0 + tid] = (float)bi2;
          }
        }
        __syncthreads();
        // ---- fused separable bicubic into qimg (exact H-then-W sum order) ----
        double scale = (double)ph / 16.0;
        double srcy = ((double)py + 0.5) * scale - 0.5;
        double fiy = floor(srcy); int iy0 = (int)fiy; double fy = srcy - fiy;
        double srcx = ((double)px + 0.5) * scale - 0.5;
        double fxx = floor(srcx); int ix0 = (int)fxx; double fx = srcx - fxx;
        double wy[4], wx[4]; int taps[16];
        #pragma unroll
        for (int m = 0; m < 4; m++) {
          wy[m] = cubicw(fy - (double)(m - 1));
          wx[m] = cubicw(fx - (double)(m - 1));
        }
        #pragma unroll
        for (int m = 0; m < 4; m++) {
          int iy = min(max(iy0 + m - 1, 0), ph - 1);
          #pragma unroll
          for (int k = 0; k < 4; k++) {
            int ix = min(max(ix0 + k - 1, 0), ph - 1);
            taps[m * 4 + k] = idx_loc[iy * ph + ix];
          }
        }
        __syncthreads();                  // taps snapshotted; lds free for qimg
        for (int c = sub; c < NC; c += 4) {
          double s = 0.0;
          #pragma unroll
          for (int k = 0; k < 4; k++) {
            double t = 0.0;               // == tt(py, ix_k): full inner H sum
            #pragma unroll
            for (int m = 0; m < 4; m++)
              t += wy[m] * (double)emb[taps[m * 4 + k] * NC + c];
            s += wx[k] * t;
          }
          qimg[c * 256 + pix] = s;
        }
      } else {
        // ---- si=4: plain gather from global idx ----
        for (int i = tid; i < NC * 256; i += TPB)
          qimg[i] = (double)emb[idx_ws[b * 256 + (i & 255)] * NC + (i >> 8)];
      }
      __syncthreads();
      // ---- phi: 0.5*x + 0.5*(conv3x3(x)+bias); residual + loss ----
      double acc[8];
      #pragma unroll
      for (int j = 0; j < 8; j++) acc[j] = 0.0;
      const float* w = phi_w + pi * NC * NC * 9;
      for (int ci = 0; ci < NC; ci++) {
        double wv[9];
        #pragma unroll
        for (int ky = 0; ky < 3; ky++) {
          int yy = py + ky - 1;
          #pragma unroll
          for (int kx = 0; kx < 3; kx++) {
            int xx = px + kx - 1;
            wv[ky * 3 + kx] = (yy >= 0 && yy < NH && xx >= 0 && xx < NW)
                              ? qimg[ci * 256 + yy * 16 + xx] : 0.0;
          }
        }
        #pragma unroll
        for (int j = 0; j < 8; j++) {
          const float* wp = w + ((sub * 8 + j) * NC + ci) * 9;  // wave-uniform
          double a = acc[j];
          #pragma unroll
          for (int k = 0; k < 9; k++) a += wv[k] * (double)wp[k];
          acc[j] = a;
        }
      }
      double lsum = 0.0;
      #pragma unroll
      for (int j = 0; j < 8; j++) {
        int co = sub * 8 + j;
        int i = co * 256 + pix;
        int gi = b * NC * 256 + i;
        double val = qimg[i] * 0.5 + (acc[j] + (double)phi_b[pi * NC + co]) * 0.5;
        double zr = z_res[gi] - val;
        z_res[gi] = zr;
        if (si == 4) out_zhat[gi] = (float)((double)z[gi] - zr);
        lsum += zr * zr;                  // z_hat - z == -z_res
      }
      __syncthreads();                    // qimg consumed
      double* red = lds;
      red[tid] = lsum; __syncthreads();
      for (int s = 512; s > 0; s >>= 1) {
        if (tid < s) red[tid] += red[tid + s];
        __syncthreads();
      }
      if (tid == 0) atomicAdd(loss_d, red[0]);
    }
    gridbar(&bars[si < 4 ? 1 + si : 6]);
  }

  if (bid == 0 && tid == 0) {
    double tot = atomicAdd(loss_d, 0.0);
    *out_loss = (float)(tot * (1.25 / (5.0 * (double)NTOT)));
  }
}

extern "C" void kernel_launch(void* const* d_in, const int* in_sizes, int n_in,
                              void* d_out, int out_size, void* d_ws, size_t ws_size,
                              hipStream_t stream) {
  const float* z     = (const float*)d_in[0];   // [64,32,16,16]
  const float* emb   = (const float*)d_in[1];   // [4096,32]
  const float* phi_w = (const float*)d_in[2];   // [4,32,32,3,3]
  const float* phi_b = (const float*)d_in[3];   // [4,32]

  float* out      = (float*)d_out;
  float* out_zhat = out;
  float* out_loss = out + NTOT;
  float* out_idx  = out + NTOT + 1; // [64,341] as floats

  double* ws     = (double*)d_ws;
  double* z_res  = ws;                       // 524288 f64
  double* emb_sq = z_res + NTOT;             // 4096 f64
  double* loss_d = emb_sq + NE;              // 1 f64
  float* emb_t   = (float*)(loss_d + 1);     // 131072 f32
  int* idx_ws    = (int*)(emb_t + NE * NC);  // 16384 int (si=4 only)
  unsigned* bars = (unsigned*)(idx_ws + NB * 256);  // 7 one-shot counters

  k_fused<<<GRID, TPB, 0, stream>>>(z, emb, phi_w, phi_b,
                                    z_res, emb_sq, loss_d,
                                    emb_t, idx_ws, bars,
                                    out_zhat, out_loss, out_idx);
}